// Round 14
// baseline (203.519 us; speedup 1.0000x reference)
//
#include <hip/hip_runtime.h>

typedef __bf16 bf16_t;
typedef __bf16 bf16x4 __attribute__((ext_vector_type(4)));
typedef __bf16 bf16x8 __attribute__((ext_vector_type(8)));
typedef float f32x4 __attribute__((ext_vector_type(4)));
typedef unsigned int u32x2 __attribute__((ext_vector_type(2)));
typedef unsigned long long u64;

#define MFMA16(a, b, c) __builtin_amdgcn_mfma_f32_16x16x32_bf16((a), (b), (c), 0, 0, 0)

#define LDG2LDS16(g, l)                                                        \
    __builtin_amdgcn_global_load_lds(                                          \
        (const __attribute__((address_space(1))) void*)(g),                    \
        (__attribute__((address_space(3))) void*)(l), 16, 0, 0)

#if __has_builtin(__builtin_amdgcn_exp2f)
#define EXP2(x) __builtin_amdgcn_exp2f(x)
#else
#define EXP2(x) exp2f(x)
#endif

// load 8 consecutive fp32 as bf16x8
__device__ inline bf16x8 load8(const float* p) {
    const f32x4 a = *(const f32x4*)p;
    const f32x4 b = *(const f32x4*)(p + 4);
    bf16x8 r;
#pragma unroll
    for (int i = 0; i < 4; i++) { r[i] = (bf16_t)a[i]; r[4 + i] = (bf16_t)b[i]; }
    return r;
}

__device__ inline u32x2 as2(bf16x4 v) {
    u32x2 r;
    __builtin_memcpy(&r, &v, 8);
    return r;
}

// 8-byte cross-lane shuffle of a packed bf16x4 (fallback path)
__device__ inline bf16x4 shfl4(bf16x4 v, int src) {
    u64 x;
    __builtin_memcpy(&x, &v, 8);
    x = __shfl(x, src, 64);
    bf16x4 r;
    __builtin_memcpy(&r, &x, 8);
    return r;
}

// ---------------------------------------------------------------------------
// fp32 -> bf16 convert: hs (4194304 el) | wqkv (3145728 el) | wo (1048576 el)
// ---------------------------------------------------------------------------
__global__ __launch_bounds__(256) void convert_kernel(const float* __restrict__ hs,
                                                      const float* __restrict__ wqkv,
                                                      const float* __restrict__ wo,
                                                      bf16_t* __restrict__ outb) {
    const size_t c = ((size_t)blockIdx.x * 256 + threadIdx.x) * 8;
    const float* src;
    size_t off;
    if (c < 4194304) { src = hs; off = c; }
    else if (c < 7340032) { src = wqkv; off = c - 4194304; }
    else { src = wo; off = c - 7340032; }
    *(bf16x8*)(outb + c) = load8(src + off);
}

// ---------------------------------------------------------------------------
// K/V swizzled layouts (MFMA-fragment order -> attn loads are base+lane*16):
//   k_sw: ((bh*128 + t>>4)*2 + (d>>5))*512 + ((t&15)+16*((d&31)>>3))*8 + (d&7)
//   v_sw: ((bh*64 + t>>5)*4 + (d>>4))*512 + ((d&15)+16*((t&31)>>3))*8 + (t&7)
// ---------------------------------------------------------------------------

// GEMM: C[M x N] = A[M x K] * B[N x K]^T, K=1024, bf16 in (pre-converted).
// m97 DMA staging, BK=32, BMx128 tile, 256 threads (4 waves).
// LDS is FRAGMENT-ORDERED: each 16x32 subtile stored as (lr, quad*8+j) ->
// subtile*512 + lane*8 + j. DMA issue i / wave w covers subtile i*4+w
// (dest = wave-uniform base + lane*16B; source row m0+(i*4+w)*16+lr, col
// quad*8 -> same 16x64B global segments as row-major = identical coalescing).
// Fragment ds_read_b128 at subtile*512 + lane*8: contiguous, ZERO bank
// conflicts, single-address reads (kills the 3.1M SQ_LDS_BANK_CONFLICT).
// MODE 0: store C row-major fp32 to outp (N = NDIM)
// MODE 1: qkv scatter epilogue with fused RoPE (wave-uniform head slot j)
template <int MODE, int NDIM, int BM>
__global__ __launch_bounds__(256) void gemm_bt(const bf16_t* __restrict__ A,
                                               const bf16_t* __restrict__ B,
                                               float* __restrict__ outp,
                                               bf16_t* __restrict__ q_ws,
                                               bf16_t* __restrict__ k_ws,
                                               bf16_t* __restrict__ v_ws,
                                               const float* __restrict__ cosb,
                                               const float* __restrict__ sinb) {
    constexpr int K = 1024;
    constexpr int IM = BM / 32;      // m-subtiles per wave (4 or 2)
    constexpr int NIA = BM / 64;     // A staging issues (2 or 1)
    __shared__ __align__(16) bf16_t As[BM * 32];
    __shared__ __align__(16) bf16_t Bs[128 * 32];

    const int tid = threadIdx.x;
    const int w = tid >> 6;
    const int lane = tid & 63;
    const int lr = lane & 15;
    const int quad = lane >> 4;
    const int m0 = blockIdx.y * BM;
    const int n0 = blockIdx.x * 128;

    // staging sources: issue i, wave w -> subtile i*4+w; per-thread element
    // (row = subtile*16 + lr, col = quad*8)
    const bf16_t* gA[NIA];
#pragma unroll
    for (int i = 0; i < NIA; i++)
        gA[i] = A + (size_t)(m0 + (i * 4 + w) * 16 + lr) * K + quad * 8;
    const bf16_t* gB0 = B + (size_t)(n0 + w * 16 + lr) * K + quad * 8;
    const bf16_t* gB1 = B + (size_t)(n0 + (4 + w) * 16 + lr) * K + quad * 8;
    bf16_t* lB0 = Bs + w * 512;
    bf16_t* lB1 = Bs + 2048 + w * 512;

    f32x4 acc[IM][4] = {};

    for (int k0 = 0; k0 < K; k0 += 32) {
#pragma unroll
        for (int i = 0; i < NIA; i++)
            LDG2LDS16(gA[i] + k0, As + i * 2048 + w * 512);
        LDG2LDS16(gB0 + k0, lB0);
        LDG2LDS16(gB1 + k0, lB1);
        __syncthreads();  // DMA drained, tile ready

        bf16x8 af[IM], bfm[4];
#pragma unroll
        for (int im = 0; im < IM; im++)
            af[im] = *(const bf16x8*)&As[(((w & 1) * IM + im) << 9) + lane * 8];
#pragma unroll
        for (int in = 0; in < 4; in++)
            bfm[in] = *(const bf16x8*)&Bs[(((w >> 1) * 4 + in) << 9) + lane * 8];
#pragma unroll
        for (int im = 0; im < IM; im++)
#pragma unroll
            for (int in = 0; in < 4; in++)
                acc[im][in] = MFMA16(af[im], bfm[in], acc[im][in]);
        __syncthreads();  // all waves done reading before next DMA
    }

    const int wm = (w & 1) * (BM / 2);
    const int wn = (w >> 1) * 64;
    if constexpr (MODE == 0) {
#pragma unroll
        for (int im = 0; im < IM; im++)
#pragma unroll
            for (int in = 0; in < 4; in++)
#pragma unroll
                for (int r = 0; r < 4; r++) {
                    const int m = m0 + wm + im * 16 + quad * 4 + r;
                    const int n = n0 + wn + in * 16 + lr;
                    outp[(size_t)m * NDIM + n] = acc[im][in][r];
                }
    } else {
        const int j = (n0 + wn) >> 6;
        if (j < 32) {
            const bool isq = (j < 16);
            const float qs = 0.125f * 1.44269504089f;
#pragma unroll
            for (int im = 0; im < IM; im++) {
#pragma unroll
                for (int r = 0; r < 4; r++) {
                    const int m = m0 + wm + im * 16 + quad * 4 + r;
                    const int b = m >> 11;
                    const int t = m & 2047;
#pragma unroll
                    for (int in = 0; in < 2; in++) {
                        const int d = in * 16 + lr;
                        const float x1 = acc[im][in][r];
                        const float x2 = acc[im][in + 2][r];
                        const float c = cosb[t * 64 + d];
                        const float s = sinb[t * 64 + d];
                        float y1 = x1 * c - x2 * s;
                        float y2 = x2 * c + x1 * s;
                        if (isq) {
                            y1 *= qs; y2 *= qs;
                            const size_t base =
                                ((size_t)(b * 16 + j) * 2048 + t) * 64 + d;
                            q_ws[base] = (bf16_t)y1;
                            q_ws[base + 32] = (bf16_t)y2;
                        } else {
                            const int bh = b * 16 + (j - 16);
                            const size_t off =
                                ((size_t)(bh * 128 + (t >> 4)) * 2) * 512 +
                                ((t & 15) + (d >> 3) * 16) * 8 + (d & 7);
                            k_ws[off] = (bf16_t)y1;
                            k_ws[off + 512] = (bf16_t)y2;
                        }
                    }
                }
            }
        } else {
#pragma unroll
            for (int im = 0; im < IM; im++)
#pragma unroll
                for (int in = 0; in < 4; in++)
#pragma unroll
                    for (int r = 0; r < 4; r++) {
                        const int m = m0 + wm + im * 16 + quad * 4 + r;
                        const int b = m >> 11;
                        const int t = m & 2047;
                        const int d = in * 16 + lr;
                        const int bh = b * 16 + (j - 32);
                        const size_t off =
                            ((size_t)(bh * 64 + (t >> 5)) * 4 + (d >> 4)) * 512 +
                            ((d & 15) + ((t & 31) >> 3) * 16) * 8 + (t & 7);
                        v_ws[off] = (bf16_t)acc[im][in][r];
                    }
        }
    }
}

// ---------------------------------------------------------------------------
// One flash tile: 16 queries (this wave), keys 0..(qt+1)*64. Transposed-score,
// max-free, LDS-free. P C-layout -> PV B-fragment via 6 permlane-swaps per
// 32-key half (HW-verified in round 13); ds_bpermute fallback.
// ---------------------------------------------------------------------------
__device__ inline void flash_tile(int qt, int quad, int lr, int query,
                                  const bf16_t* __restrict__ kbase,
                                  const bf16_t* __restrict__ vbase,
                                  bf16x8 qlo, bf16x8 qhi,
                                  f32x4* o, float& lrun) {
    bf16x8 kc[8];
#pragma unroll
    for (int n = 0; n < 4; n++) {
        kc[2 * n] = *(const bf16x8*)(kbase + (size_t)(n * 2) * 512);
        kc[2 * n + 1] = *(const bf16x8*)(kbase + (size_t)(n * 2 + 1) * 512);
    }

    for (int kb = 0; kb <= qt; kb++) {
        bf16x8 vv[2][4];
#pragma unroll
        for (int hh = 0; hh < 2; hh++)
#pragma unroll
            for (int n = 0; n < 4; n++)
                vv[hh][n] = *(const bf16x8*)(vbase +
                    (size_t)((kb * 2 + hh) * 4 + n) * 512);

        const int kbn = (kb < qt) ? kb + 1 : kb;
        bf16x8 kn[8];
#pragma unroll
        for (int n = 0; n < 4; n++) {
            kn[2 * n] = *(const bf16x8*)(kbase + (size_t)((kbn * 4 + n) * 2) * 512);
            kn[2 * n + 1] = *(const bf16x8*)(kbase + (size_t)((kbn * 4 + n) * 2 + 1) * 512);
        }

        const int u0 = kb * 64;
        f32x4 s[4];
#pragma unroll
        for (int n = 0; n < 4; n++) {
            const f32x4 z = {};
            s[n] = MFMA16(kc[2 * n], qlo, z);
            s[n] = MFMA16(kc[2 * n + 1], qhi, s[n]);
        }

        if (kb == qt) {  // diagonal 64-key block: causal mask (key > query)
#pragma unroll
            for (int n = 0; n < 4; n++)
#pragma unroll
                for (int r = 0; r < 4; r++)
                    if (u0 + n * 16 + quad * 4 + r > query) s[n][r] = -1e9f;
        }

        f32x4 p[4];
#pragma unroll
        for (int n = 0; n < 4; n++)
#pragma unroll
            for (int r = 0; r < 4; r++) p[n][r] = EXP2(s[n][r]);

        lrun += ((p[0][0] + p[0][1]) + (p[0][2] + p[0][3])) +
                ((p[1][0] + p[1][1]) + (p[1][2] + p[1][3])) +
                ((p[2][0] + p[2][1]) + (p[2][2] + p[2][3])) +
                ((p[3][0] + p[3][1]) + (p[3][2] + p[3][3]));

        bf16x4 pb[4];
#pragma unroll
        for (int n = 0; n < 4; n++)
#pragma unroll
            for (int r = 0; r < 4; r++) pb[n][r] = (bf16_t)p[n][r];

#pragma unroll
        for (int hh = 0; hh < 2; hh++) {  // 32-key halves
            bf16x8 pf;
#if __has_builtin(__builtin_amdgcn_permlane16_swap) && \
    __has_builtin(__builtin_amdgcn_permlane32_swap)
            const u32x2 P0 = as2(pb[2 * hh]);
            const u32x2 P1 = as2(pb[2 * hh + 1]);
            const u32x2 s1a = __builtin_amdgcn_permlane16_swap(P0[0], P0[1], false, false);
            const u32x2 s1b = __builtin_amdgcn_permlane16_swap(P1[0], P1[1], false, false);
            const u32x2 s2a = __builtin_amdgcn_permlane32_swap(s1a[0], s1b[0], false, false);
            const u32x2 s2b = __builtin_amdgcn_permlane32_swap(s1a[1], s1b[1], false, false);
            const u32x2 s3a = __builtin_amdgcn_permlane16_swap(s2a[0], s2a[1], false, false);
            const u32x2 s3b = __builtin_amdgcn_permlane16_swap(s2b[0], s2b[1], false, false);
            const unsigned pfd[4] = {s3a[0], s3a[1], s3b[0], s3b[1]};
            __builtin_memcpy(&pf, pfd, 16);
#else
            const int srcLow = ((quad & 1) << 5) + lr;
            const int srcHigh = srcLow + 16;
            const bool loSel = (quad < 2);
            const bf16x4 a0 = shfl4(pb[2 * hh], srcLow);
            const bf16x4 a1 = shfl4(pb[2 * hh + 1], srcLow);
            const bf16x4 b0 = shfl4(pb[2 * hh], srcHigh);
            const bf16x4 b1 = shfl4(pb[2 * hh + 1], srcHigh);
            const bf16x4 lo = loSel ? a0 : a1;
            const bf16x4 hi = loSel ? b0 : b1;
#pragma unroll
            for (int r = 0; r < 4; r++) { pf[r] = lo[r]; pf[4 + r] = hi[r]; }
#endif
#pragma unroll
            for (int n = 0; n < 4; n++)
                o[n] = MFMA16(vv[hh][n], pf, o[n]);
        }

#pragma unroll
        for (int i = 0; i < 8; i++) kc[i] = kn[i];
    }
}

// ---------------------------------------------------------------------------
// Flash attention: 1024 WGs (4/CU -> ~47% occupancy for latency hiding),
// LPT dispatch (longest qt first). 4 independent waves, no barriers, no LDS.
// ---------------------------------------------------------------------------
__global__ __launch_bounds__(256) void attn_kernel(const bf16_t* __restrict__ q_ws,
                                                   const bf16_t* __restrict__ k_ws,
                                                   const bf16_t* __restrict__ v_ws,
                                                   bf16_t* __restrict__ ctx) {
    const int tid = threadIdx.x;
    const int w = tid >> 6;
    const int lane = tid & 63;
    const int lr = lane & 15;
    const int quad = lane >> 4;
    const int bh = blockIdx.x & 31;
    const int qt = 31 - (blockIdx.x >> 5);  // LPT
    const int b = bh >> 4;
    const int hd = bh & 15;
    const int trow = qt * 64 + w * 16;
    const int query = trow + lr;

    const bf16_t* kbase = k_ws + (size_t)bh * 131072 + lane * 8;
    const bf16_t* vbase = v_ws + (size_t)bh * 131072 + lane * 8;

    const bf16_t* qb = q_ws + ((size_t)bh * 2048 + trow + lr) * 64 + quad * 8;
    const bf16x8 qlo = *(const bf16x8*)qb;
    const bf16x8 qhi = *(const bf16x8*)(qb + 32);

    f32x4 o[4] = {};
    float lrun = 0.0f;
    flash_tile(qt, quad, lr, query, kbase, vbase, qlo, qhi, o, lrun);

    lrun += __shfl_xor(lrun, 16);
    lrun += __shfl_xor(lrun, 32);

    const float inv = 1.0f / fmaxf(lrun, 1e-30f);
    const size_t base = ((size_t)b * 2048 + query) * 1024 + hd * 64 + quad * 4;
#pragma unroll
    for (int n = 0; n < 4; n++) {
        bf16x4 ob;
#pragma unroll
        for (int r = 0; r < 4; r++) ob[r] = (bf16_t)(o[n][r] * inv);
        *(bf16x4*)&ctx[base + n * 16] = ob;
    }
}

// ---------------------------------------------------------------------------
// Launcher. Inputs fp32, output fp32.
// ws bytes: [0,8M) hs_b -> (after gemm1) ctx overlay | [8M,14M) wqkv_b |
//           [14M,16M) wo_b | [16M,24M) q | [24M,32M) k | [32M,40M) v.
// ---------------------------------------------------------------------------
extern "C" void kernel_launch(void* const* d_in, const int* in_sizes, int n_in,
                              void* d_out, int out_size, void* d_ws, size_t ws_size,
                              hipStream_t stream) {
    const float* hs = (const float*)d_in[0];
    const float* cosb = (const float*)d_in[1];
    const float* sinb = (const float*)d_in[2];
    const float* wqkv = (const float*)d_in[3];
    const float* wo = (const float*)d_in[4];
    float* out = (float*)d_out;

    char* ws = (char*)d_ws;
    bf16_t* hs_b = (bf16_t*)(ws);
    bf16_t* wqkv_b = hs_b + 4194304;
    bf16_t* wo_b = hs_b + 7340032;
    bf16_t* q_ws = (bf16_t*)(ws + (size_t)(16u << 20));
    bf16_t* k_ws = (bf16_t*)(ws + (size_t)(24u << 20));
    bf16_t* v_ws = (bf16_t*)(ws + (size_t)(32u << 20));
    bf16_t* ctx = (bf16_t*)(ws);  // overlays hs_b (dead after gemm1)

    const dim3 blk(256);

    // 0) fp32 -> bf16 convert (hs | wqkv | wo packed)
    convert_kernel<<<dim3(4096), blk, 0, stream>>>(hs, wqkv, wo, hs_b);

    // 1) QKV projection + fused RoPE + scatter: M=4096, N=3072, K=1024
    gemm_bt<1, 3072, 128><<<dim3(24, 32), blk, 0, stream>>>(
        hs_b, wqkv_b, nullptr, q_ws, k_ws, v_ws, cosb, sinb);

    // 2) Flash attention -> ctx [B,T,1024] (bf16)
    attn_kernel<<<dim3(1024), blk, 0, stream>>>(q_ws, k_ws, v_ws, ctx);

    // 3) Output projection: M=4096, N=1024, K=1024 (BM=64 -> 512 blocks)
    gemm_bt<0, 1024, 64><<<dim3(8, 64), blk, 0, stream>>>(
        ctx, wo_b, out, nullptr, nullptr, nullptr, nullptr, nullptr);
}

// Round 15
// 196.849 us; speedup vs baseline: 1.0339x; 1.0339x over previous
//
#include <hip/hip_runtime.h>

typedef __bf16 bf16_t;
typedef __bf16 bf16x4 __attribute__((ext_vector_type(4)));
typedef __bf16 bf16x8 __attribute__((ext_vector_type(8)));
typedef float f32x4 __attribute__((ext_vector_type(4)));
typedef unsigned int u32x2 __attribute__((ext_vector_type(2)));
typedef unsigned long long u64;

#define MFMA16(a, b, c) __builtin_amdgcn_mfma_f32_16x16x32_bf16((a), (b), (c), 0, 0, 0)

#define LDG2LDS16(g, l)                                                        \
    __builtin_amdgcn_global_load_lds(                                          \
        (const __attribute__((address_space(1))) void*)(g),                    \
        (__attribute__((address_space(3))) void*)(l), 16, 0, 0)

#if __has_builtin(__builtin_amdgcn_exp2f)
#define EXP2(x) __builtin_amdgcn_exp2f(x)
#else
#define EXP2(x) exp2f(x)
#endif

// load 8 consecutive fp32 as bf16x8
__device__ inline bf16x8 load8(const float* p) {
    const f32x4 a = *(const f32x4*)p;
    const f32x4 b = *(const f32x4*)(p + 4);
    bf16x8 r;
#pragma unroll
    for (int i = 0; i < 4; i++) { r[i] = (bf16_t)a[i]; r[4 + i] = (bf16_t)b[i]; }
    return r;
}

__device__ inline u32x2 as2(bf16x4 v) {
    u32x2 r;
    __builtin_memcpy(&r, &v, 8);
    return r;
}

// 8-byte cross-lane shuffle of a packed bf16x4 (fallback path)
__device__ inline bf16x4 shfl4(bf16x4 v, int src) {
    u64 x;
    __builtin_memcpy(&x, &v, 8);
    x = __shfl(x, src, 64);
    bf16x4 r;
    __builtin_memcpy(&r, &x, 8);
    return r;
}

// ---------------------------------------------------------------------------
// fp32 -> bf16 convert: hs (4194304 el) | wqkv (3145728 el) | wo (1048576 el)
// ---------------------------------------------------------------------------
__global__ __launch_bounds__(256) void convert_kernel(const float* __restrict__ hs,
                                                      const float* __restrict__ wqkv,
                                                      const float* __restrict__ wo,
                                                      bf16_t* __restrict__ outb) {
    const size_t c = ((size_t)blockIdx.x * 256 + threadIdx.x) * 8;
    const float* src;
    size_t off;
    if (c < 4194304) { src = hs; off = c; }
    else if (c < 7340032) { src = wqkv; off = c - 4194304; }
    else { src = wo; off = c - 7340032; }
    *(bf16x8*)(outb + c) = load8(src + off);
}

// ---------------------------------------------------------------------------
// K/V swizzled layouts (MFMA-fragment order -> attn loads are base+lane*16):
//   k_sw: ((bh*128 + t>>4)*2 + (d>>5))*512 + ((t&15)+16*((d&31)>>3))*8 + (d&7)
//   v_sw: ((bh*64 + t>>5)*4 + (d>>4))*512 + ((d&15)+16*((t&31)>>3))*8 + (t&7)
// ---------------------------------------------------------------------------

// GEMM: C[M x N] = A[M x K] * B[N x K]^T, K=1024, bf16 in (pre-converted).
// m97 DMA staging (r12-proven source map: 4 consecutive lanes cover one 64B
// row-segment -> full-width coalescing), row-major LDS stride 32.
// BK=64 via TWIN BUFFERS: two 32-wide K-slices staged per barrier pair ->
// half the vmcnt(0) barrier drains, 2x MFMA per drain (32/wave). 32KB LDS.
// MODE 0: store C row-major fp32 to outp (N = NDIM)
// MODE 1: qkv scatter epilogue with fused RoPE (wave-uniform head slot j)
template <int MODE, int NDIM, int BM>
__global__ __launch_bounds__(256) void gemm_bt(const bf16_t* __restrict__ A,
                                               const bf16_t* __restrict__ B,
                                               float* __restrict__ outp,
                                               bf16_t* __restrict__ q_ws,
                                               bf16_t* __restrict__ k_ws,
                                               bf16_t* __restrict__ v_ws,
                                               const float* __restrict__ cosb,
                                               const float* __restrict__ sinb) {
    constexpr int K = 1024;
    constexpr int IM = BM / 32;
    __shared__ __align__(16) bf16_t As[2][BM * 32];
    __shared__ __align__(16) bf16_t Bs[2][128 * 32];

    const int tid = threadIdx.x;
    const int w = tid >> 6;
    const int lane = tid & 63;
    const int lr = lane & 15;
    const int quad = lane >> 4;
    const int m0 = blockIdx.y * BM;
    const int n0 = blockIdx.x * 128;
    const int wm = (w & 1) * (BM / 2);
    const int wn = (w >> 1) * 64;

    // staging map (r12-proven): thread tid -> row tid>>2, k-chunk (tid&3)*8
    const int srow = tid >> 2;
    const int skk = (tid & 3) * 8;
    const bf16_t* gA0 = A + (size_t)(m0 + srow) * K + skk;
    const bf16_t* gA1 = gA0 + (size_t)64 * K;  // only when BM==128
    const bf16_t* gB0 = B + (size_t)(n0 + srow) * K + skk;
    const bf16_t* gB1 = gB0 + (size_t)64 * K;

    f32x4 acc[IM][4] = {};

    for (int k0 = 0; k0 < K; k0 += 64) {
#pragma unroll
        for (int h = 0; h < 2; h++) {
            const int kk = k0 + h * 32;
            LDG2LDS16(gA0 + kk, &As[h][w * 512]);
            if constexpr (BM == 128) LDG2LDS16(gA1 + kk, &As[h][2048 + w * 512]);
            LDG2LDS16(gB0 + kk, &Bs[h][w * 512]);
            LDG2LDS16(gB1 + kk, &Bs[h][2048 + w * 512]);
        }
        __syncthreads();  // DMA drained (vmcnt(0)), both slices ready

#pragma unroll
        for (int h = 0; h < 2; h++) {
            bf16x8 af[IM], bfm[4];
#pragma unroll
            for (int im = 0; im < IM; im++)
                af[im] = *(const bf16x8*)&As[h][(wm + im * 16 + lr) * 32 + quad * 8];
#pragma unroll
            for (int in = 0; in < 4; in++)
                bfm[in] = *(const bf16x8*)&Bs[h][(wn + in * 16 + lr) * 32 + quad * 8];
#pragma unroll
            for (int im = 0; im < IM; im++)
#pragma unroll
                for (int in = 0; in < 4; in++)
                    acc[im][in] = MFMA16(af[im], bfm[in], acc[im][in]);
        }
        __syncthreads();  // all waves done reading before next DMA
    }

    if constexpr (MODE == 0) {
#pragma unroll
        for (int im = 0; im < IM; im++)
#pragma unroll
            for (int in = 0; in < 4; in++)
#pragma unroll
                for (int r = 0; r < 4; r++) {
                    const int m = m0 + wm + im * 16 + quad * 4 + r;
                    const int n = n0 + wn + in * 16 + lr;
                    outp[(size_t)m * NDIM + n] = acc[im][in][r];
                }
    } else {
        const int j = (n0 + wn) >> 6;
        if (j < 32) {
            const bool isq = (j < 16);
            const float qs = 0.125f * 1.44269504089f;
#pragma unroll
            for (int im = 0; im < IM; im++) {
#pragma unroll
                for (int r = 0; r < 4; r++) {
                    const int m = m0 + wm + im * 16 + quad * 4 + r;
                    const int b = m >> 11;
                    const int t = m & 2047;
#pragma unroll
                    for (int in = 0; in < 2; in++) {
                        const int d = in * 16 + lr;
                        const float x1 = acc[im][in][r];
                        const float x2 = acc[im][in + 2][r];
                        const float c = cosb[t * 64 + d];
                        const float s = sinb[t * 64 + d];
                        float y1 = x1 * c - x2 * s;
                        float y2 = x2 * c + x1 * s;
                        if (isq) {
                            y1 *= qs; y2 *= qs;
                            const size_t base =
                                ((size_t)(b * 16 + j) * 2048 + t) * 64 + d;
                            q_ws[base] = (bf16_t)y1;
                            q_ws[base + 32] = (bf16_t)y2;
                        } else {
                            const int bh = b * 16 + (j - 16);
                            const size_t off =
                                ((size_t)(bh * 128 + (t >> 4)) * 2) * 512 +
                                ((t & 15) + (d >> 3) * 16) * 8 + (d & 7);
                            k_ws[off] = (bf16_t)y1;
                            k_ws[off + 512] = (bf16_t)y2;
                        }
                    }
                }
            }
        } else {
#pragma unroll
            for (int im = 0; im < IM; im++)
#pragma unroll
                for (int in = 0; in < 4; in++)
#pragma unroll
                    for (int r = 0; r < 4; r++) {
                        const int m = m0 + wm + im * 16 + quad * 4 + r;
                        const int b = m >> 11;
                        const int t = m & 2047;
                        const int d = in * 16 + lr;
                        const int bh = b * 16 + (j - 32);
                        const size_t off =
                            ((size_t)(bh * 64 + (t >> 5)) * 4 + (d >> 4)) * 512 +
                            ((d & 15) + ((t & 31) >> 3) * 16) * 8 + (t & 7);
                        v_ws[off] = (bf16_t)acc[im][in][r];
                    }
        }
    }
}

// ---------------------------------------------------------------------------
// One flash tile: 16 queries (this wave), keys 0..(qt+1)*64. Transposed-score,
// max-free, LDS-free. P C-layout -> PV B-fragment via 6 permlane-swaps per
// 32-key half (HW-verified); ds_bpermute fallback.
// ---------------------------------------------------------------------------
__device__ inline void flash_tile(int qt, int quad, int lr, int query,
                                  const bf16_t* __restrict__ kbase,
                                  const bf16_t* __restrict__ vbase,
                                  bf16x8 qlo, bf16x8 qhi,
                                  f32x4* o, float& lrun) {
    bf16x8 kc[8];
#pragma unroll
    for (int n = 0; n < 4; n++) {
        kc[2 * n] = *(const bf16x8*)(kbase + (size_t)(n * 2) * 512);
        kc[2 * n + 1] = *(const bf16x8*)(kbase + (size_t)(n * 2 + 1) * 512);
    }

    for (int kb = 0; kb <= qt; kb++) {
        bf16x8 vv[2][4];
#pragma unroll
        for (int hh = 0; hh < 2; hh++)
#pragma unroll
            for (int n = 0; n < 4; n++)
                vv[hh][n] = *(const bf16x8*)(vbase +
                    (size_t)((kb * 2 + hh) * 4 + n) * 512);

        const int kbn = (kb < qt) ? kb + 1 : kb;
        bf16x8 kn[8];
#pragma unroll
        for (int n = 0; n < 4; n++) {
            kn[2 * n] = *(const bf16x8*)(kbase + (size_t)((kbn * 4 + n) * 2) * 512);
            kn[2 * n + 1] = *(const bf16x8*)(kbase + (size_t)((kbn * 4 + n) * 2 + 1) * 512);
        }

        const int u0 = kb * 64;
        f32x4 s[4];
#pragma unroll
        for (int n = 0; n < 4; n++) {
            const f32x4 z = {};
            s[n] = MFMA16(kc[2 * n], qlo, z);
            s[n] = MFMA16(kc[2 * n + 1], qhi, s[n]);
        }

        if (kb == qt) {  // diagonal 64-key block: causal mask (key > query)
#pragma unroll
            for (int n = 0; n < 4; n++)
#pragma unroll
                for (int r = 0; r < 4; r++)
                    if (u0 + n * 16 + quad * 4 + r > query) s[n][r] = -1e9f;
        }

        f32x4 p[4];
#pragma unroll
        for (int n = 0; n < 4; n++)
#pragma unroll
            for (int r = 0; r < 4; r++) p[n][r] = EXP2(s[n][r]);

        lrun += ((p[0][0] + p[0][1]) + (p[0][2] + p[0][3])) +
                ((p[1][0] + p[1][1]) + (p[1][2] + p[1][3])) +
                ((p[2][0] + p[2][1]) + (p[2][2] + p[2][3])) +
                ((p[3][0] + p[3][1]) + (p[3][2] + p[3][3]));

        bf16x4 pb[4];
#pragma unroll
        for (int n = 0; n < 4; n++)
#pragma unroll
            for (int r = 0; r < 4; r++) pb[n][r] = (bf16_t)p[n][r];

#pragma unroll
        for (int hh = 0; hh < 2; hh++) {  // 32-key halves
            bf16x8 pf;
#if __has_builtin(__builtin_amdgcn_permlane16_swap) && \
    __has_builtin(__builtin_amdgcn_permlane32_swap)
            const u32x2 P0 = as2(pb[2 * hh]);
            const u32x2 P1 = as2(pb[2 * hh + 1]);
            const u32x2 s1a = __builtin_amdgcn_permlane16_swap(P0[0], P0[1], false, false);
            const u32x2 s1b = __builtin_amdgcn_permlane16_swap(P1[0], P1[1], false, false);
            const u32x2 s2a = __builtin_amdgcn_permlane32_swap(s1a[0], s1b[0], false, false);
            const u32x2 s2b = __builtin_amdgcn_permlane32_swap(s1a[1], s1b[1], false, false);
            const u32x2 s3a = __builtin_amdgcn_permlane16_swap(s2a[0], s2a[1], false, false);
            const u32x2 s3b = __builtin_amdgcn_permlane16_swap(s2b[0], s2b[1], false, false);
            const unsigned pfd[4] = {s3a[0], s3a[1], s3b[0], s3b[1]};
            __builtin_memcpy(&pf, pfd, 16);
#else
            const int srcLow = ((quad & 1) << 5) + lr;
            const int srcHigh = srcLow + 16;
            const bool loSel = (quad < 2);
            const bf16x4 a0 = shfl4(pb[2 * hh], srcLow);
            const bf16x4 a1 = shfl4(pb[2 * hh + 1], srcLow);
            const bf16x4 b0 = shfl4(pb[2 * hh], srcHigh);
            const bf16x4 b1 = shfl4(pb[2 * hh + 1], srcHigh);
            const bf16x4 lo = loSel ? a0 : a1;
            const bf16x4 hi = loSel ? b0 : b1;
#pragma unroll
            for (int r = 0; r < 4; r++) { pf[r] = lo[r]; pf[4 + r] = hi[r]; }
#endif
#pragma unroll
            for (int n = 0; n < 4; n++)
                o[n] = MFMA16(vv[hh][n], pf, o[n]);
        }

#pragma unroll
        for (int i = 0; i < 8; i++) kc[i] = kn[i];
    }
}

// ---------------------------------------------------------------------------
// Flash attention, paired tiles (r13-proven): 512 WGs, WG = (pr, bh) handles
// qt = pr AND qt = 31-pr -> every WG exactly 33 iterations, every CU identical.
// 4 independent waves, no barriers, no LDS.
// ---------------------------------------------------------------------------
__global__ __launch_bounds__(256) void attn_kernel(const bf16_t* __restrict__ q_ws,
                                                   const bf16_t* __restrict__ k_ws,
                                                   const bf16_t* __restrict__ v_ws,
                                                   bf16_t* __restrict__ ctx) {
    const int tid = threadIdx.x;
    const int w = tid >> 6;
    const int lane = tid & 63;
    const int lr = lane & 15;
    const int quad = lane >> 4;
    const int bh = blockIdx.x & 31;
    const int pr = blockIdx.x >> 5;  // 0..15
    const int b = bh >> 4;
    const int hd = bh & 15;

    const bf16_t* kbase = k_ws + (size_t)bh * 131072 + lane * 8;
    const bf16_t* vbase = v_ws + (size_t)bh * 131072 + lane * 8;

#pragma unroll
    for (int half = 0; half < 2; half++) {
        const int qt = half ? (31 - pr) : pr;
        const int trow = qt * 64 + w * 16;
        const int query = trow + lr;

        const bf16_t* qb = q_ws + ((size_t)bh * 2048 + trow + lr) * 64 + quad * 8;
        const bf16x8 qlo = *(const bf16x8*)qb;
        const bf16x8 qhi = *(const bf16x8*)(qb + 32);

        f32x4 o[4] = {};
        float lrun = 0.0f;
        flash_tile(qt, quad, lr, query, kbase, vbase, qlo, qhi, o, lrun);

        lrun += __shfl_xor(lrun, 16);
        lrun += __shfl_xor(lrun, 32);

        const float inv = 1.0f / fmaxf(lrun, 1e-30f);
        const size_t base = ((size_t)b * 2048 + query) * 1024 + hd * 64 + quad * 4;
#pragma unroll
        for (int n = 0; n < 4; n++) {
            bf16x4 ob;
#pragma unroll
            for (int r = 0; r < 4; r++) ob[r] = (bf16_t)(o[n][r] * inv);
            *(bf16x4*)&ctx[base + n * 16] = ob;
        }
    }
}

// ---------------------------------------------------------------------------
// Launcher. Inputs fp32, output fp32.
// ws bytes: [0,8M) hs_b -> (after gemm1) ctx overlay | [8M,14M) wqkv_b |
//           [14M,16M) wo_b | [16M,24M) q | [24M,32M) k | [32M,40M) v.
// ---------------------------------------------------------------------------
extern "C" void kernel_launch(void* const* d_in, const int* in_sizes, int n_in,
                              void* d_out, int out_size, void* d_ws, size_t ws_size,
                              hipStream_t stream) {
    const float* hs = (const float*)d_in[0];
    const float* cosb = (const float*)d_in[1];
    const float* sinb = (const float*)d_in[2];
    const float* wqkv = (const float*)d_in[3];
    const float* wo = (const float*)d_in[4];
    float* out = (float*)d_out;

    char* ws = (char*)d_ws;
    bf16_t* hs_b = (bf16_t*)(ws);
    bf16_t* wqkv_b = hs_b + 4194304;
    bf16_t* wo_b = hs_b + 7340032;
    bf16_t* q_ws = (bf16_t*)(ws + (size_t)(16u << 20));
    bf16_t* k_ws = (bf16_t*)(ws + (size_t)(24u << 20));
    bf16_t* v_ws = (bf16_t*)(ws + (size_t)(32u << 20));
    bf16_t* ctx = (bf16_t*)(ws);  // overlays hs_b (dead after gemm1)

    const dim3 blk(256);

    // 0) fp32 -> bf16 convert (hs | wqkv | wo packed)
    convert_kernel<<<dim3(4096), blk, 0, stream>>>(hs, wqkv, wo, hs_b);

    // 1) QKV projection + fused RoPE + scatter: M=4096, N=3072, K=1024
    gemm_bt<1, 3072, 128><<<dim3(24, 32), blk, 0, stream>>>(
        hs_b, wqkv_b, nullptr, q_ws, k_ws, v_ws, cosb, sinb);

    // 2) Flash attention (paired tiles) -> ctx [B,T,1024] (bf16)
    attn_kernel<<<dim3(512), blk, 0, stream>>>(q_ws, k_ws, v_ws, ctx);

    // 3) Output projection: M=4096, N=1024, K=1024 (BM=64 -> 512 blocks)
    gemm_bt<0, 1024, 64><<<dim3(8, 64), blk, 0, stream>>>(
        ctx, wo_b, out, nullptr, nullptr, nullptr, nullptr, nullptr);
}

// Round 16
// 182.389 us; speedup vs baseline: 1.1159x; 1.0793x over previous
//
#include <hip/hip_runtime.h>

typedef __bf16 bf16_t;
typedef __bf16 bf16x4 __attribute__((ext_vector_type(4)));
typedef __bf16 bf16x8 __attribute__((ext_vector_type(8)));
typedef float f32x4 __attribute__((ext_vector_type(4)));
typedef unsigned int u32x2 __attribute__((ext_vector_type(2)));
typedef unsigned long long u64;

#define MFMA16(a, b, c) __builtin_amdgcn_mfma_f32_16x16x32_bf16((a), (b), (c), 0, 0, 0)

#define LDG2LDS16(g, l)                                                        \
    __builtin_amdgcn_global_load_lds(                                          \
        (const __attribute__((address_space(1))) void*)(g),                    \
        (__attribute__((address_space(3))) void*)(l), 16, 0, 0)

#if __has_builtin(__builtin_amdgcn_exp2f)
#define EXP2(x) __builtin_amdgcn_exp2f(x)
#else
#define EXP2(x) exp2f(x)
#endif

// load 8 consecutive fp32 as bf16x8
__device__ inline bf16x8 load8(const float* p) {
    const f32x4 a = *(const f32x4*)p;
    const f32x4 b = *(const f32x4*)(p + 4);
    bf16x8 r;
#pragma unroll
    for (int i = 0; i < 4; i++) { r[i] = (bf16_t)a[i]; r[4 + i] = (bf16_t)b[i]; }
    return r;
}

__device__ inline u32x2 as2(bf16x4 v) {
    u32x2 r;
    __builtin_memcpy(&r, &v, 8);
    return r;
}

// 8-byte cross-lane shuffle of a packed bf16x4 (fallback path)
__device__ inline bf16x4 shfl4(bf16x4 v, int src) {
    u64 x;
    __builtin_memcpy(&x, &v, 8);
    x = __shfl(x, src, 64);
    bf16x4 r;
    __builtin_memcpy(&r, &x, 8);
    return r;
}

// P C-layout (2 packed bf16x4 regs = 32 keys x this query) -> PV B-fragment,
// via 6 permlane-swaps (HW-verified r13); ds_bpermute fallback.
__device__ inline bf16x8 ptrans(bf16x4 pA, bf16x4 pB, int quad, int lr) {
    bf16x8 pf;
#if __has_builtin(__builtin_amdgcn_permlane16_swap) && \
    __has_builtin(__builtin_amdgcn_permlane32_swap)
    const u32x2 P0 = as2(pA);
    const u32x2 P1 = as2(pB);
    const u32x2 s1a = __builtin_amdgcn_permlane16_swap(P0[0], P0[1], false, false);
    const u32x2 s1b = __builtin_amdgcn_permlane16_swap(P1[0], P1[1], false, false);
    const u32x2 s2a = __builtin_amdgcn_permlane32_swap(s1a[0], s1b[0], false, false);
    const u32x2 s2b = __builtin_amdgcn_permlane32_swap(s1a[1], s1b[1], false, false);
    const u32x2 s3a = __builtin_amdgcn_permlane16_swap(s2a[0], s2a[1], false, false);
    const u32x2 s3b = __builtin_amdgcn_permlane16_swap(s2b[0], s2b[1], false, false);
    const unsigned pfd[4] = {s3a[0], s3a[1], s3b[0], s3b[1]};
    __builtin_memcpy(&pf, pfd, 16);
#else
    const int srcLow = ((quad & 1) << 5) + lr;
    const int srcHigh = srcLow + 16;
    const bool loSel = (quad < 2);
    const bf16x4 a0 = shfl4(pA, srcLow);
    const bf16x4 a1 = shfl4(pB, srcLow);
    const bf16x4 b0 = shfl4(pA, srcHigh);
    const bf16x4 b1 = shfl4(pB, srcHigh);
    const bf16x4 lo = loSel ? a0 : a1;
    const bf16x4 hi = loSel ? b0 : b1;
#pragma unroll
    for (int r = 0; r < 4; r++) { pf[r] = lo[r]; pf[4 + r] = hi[r]; }
#endif
    return pf;
}

// ---------------------------------------------------------------------------
// fp32 -> bf16 convert: hs (4194304 el) | wqkv (3145728 el) | wo (1048576 el)
// ---------------------------------------------------------------------------
__global__ __launch_bounds__(256) void convert_kernel(const float* __restrict__ hs,
                                                      const float* __restrict__ wqkv,
                                                      const float* __restrict__ wo,
                                                      bf16_t* __restrict__ outb) {
    const size_t c = ((size_t)blockIdx.x * 256 + threadIdx.x) * 8;
    const float* src;
    size_t off;
    if (c < 4194304) { src = hs; off = c; }
    else if (c < 7340032) { src = wqkv; off = c - 4194304; }
    else { src = wo; off = c - 7340032; }
    *(bf16x8*)(outb + c) = load8(src + off);
}

// ---------------------------------------------------------------------------
// K/V swizzled layouts (MFMA-fragment order -> attn loads are base+lane*16):
//   k_sw: ((bh*128 + t>>4)*2 + (d>>5))*512 + ((t&15)+16*((d&31)>>3))*8 + (d&7)
//   v_sw: ((bh*64 + t>>5)*4 + (d>>4))*512 + ((d&15)+16*((t&31)>>3))*8 + (t&7)
// ---------------------------------------------------------------------------

// GEMM (r13-proven, 55us): m97 DMA staging, row-major LDS stride 32, BK=32.
// MODE 0: store C row-major fp32 to outp (N = NDIM)
// MODE 1: qkv scatter epilogue with fused RoPE (wave-uniform head slot j)
template <int MODE, int NDIM, int BM>
__global__ __launch_bounds__(256) void gemm_bt(const bf16_t* __restrict__ A,
                                               const bf16_t* __restrict__ B,
                                               float* __restrict__ outp,
                                               bf16_t* __restrict__ q_ws,
                                               bf16_t* __restrict__ k_ws,
                                               bf16_t* __restrict__ v_ws,
                                               const float* __restrict__ cosb,
                                               const float* __restrict__ sinb) {
    constexpr int K = 1024;
    constexpr int IM = BM / 32;
    __shared__ __align__(16) bf16_t As[BM * 32];
    __shared__ __align__(16) bf16_t Bs[128 * 32];

    const int tid = threadIdx.x;
    const int w = tid >> 6;
    const int lane = tid & 63;
    const int lr = lane & 15;
    const int quad = lane >> 4;
    const int m0 = blockIdx.y * BM;
    const int n0 = blockIdx.x * 128;
    const int wm = (w & 1) * (BM / 2);
    const int wn = (w >> 1) * 64;

    const int srow = tid >> 2;
    const int skk = (tid & 3) * 8;
    const bf16_t* gA0 = A + (size_t)(m0 + srow) * K + skk;
    const bf16_t* gA1 = gA0 + (size_t)64 * K;  // only when BM==128
    const bf16_t* gB0 = B + (size_t)(n0 + srow) * K + skk;
    const bf16_t* gB1 = gB0 + (size_t)64 * K;
    bf16_t* lA0 = As + w * 512;
    bf16_t* lA1 = As + 2048 + w * 512;
    bf16_t* lB0 = Bs + w * 512;
    bf16_t* lB1 = Bs + 2048 + w * 512;

    f32x4 acc[IM][4] = {};

    for (int k0 = 0; k0 < K; k0 += 32) {
        LDG2LDS16(gA0 + k0, lA0);
        if constexpr (BM == 128) LDG2LDS16(gA1 + k0, lA1);
        LDG2LDS16(gB0 + k0, lB0);
        LDG2LDS16(gB1 + k0, lB1);
        __syncthreads();

        bf16x8 af[IM], bfm[4];
#pragma unroll
        for (int im = 0; im < IM; im++)
            af[im] = *(const bf16x8*)&As[(wm + im * 16 + lr) * 32 + quad * 8];
#pragma unroll
        for (int in = 0; in < 4; in++)
            bfm[in] = *(const bf16x8*)&Bs[(wn + in * 16 + lr) * 32 + quad * 8];
#pragma unroll
        for (int im = 0; im < IM; im++)
#pragma unroll
            for (int in = 0; in < 4; in++)
                acc[im][in] = MFMA16(af[im], bfm[in], acc[im][in]);
        __syncthreads();
    }

    if constexpr (MODE == 0) {
#pragma unroll
        for (int im = 0; im < IM; im++)
#pragma unroll
            for (int in = 0; in < 4; in++)
#pragma unroll
                for (int r = 0; r < 4; r++) {
                    const int m = m0 + wm + im * 16 + quad * 4 + r;
                    const int n = n0 + wn + in * 16 + lr;
                    outp[(size_t)m * NDIM + n] = acc[im][in][r];
                }
    } else {
        const int j = (n0 + wn) >> 6;
        if (j < 32) {
            const bool isq = (j < 16);
            const float qs = 0.125f * 1.44269504089f;
#pragma unroll
            for (int im = 0; im < IM; im++) {
#pragma unroll
                for (int r = 0; r < 4; r++) {
                    const int m = m0 + wm + im * 16 + quad * 4 + r;
                    const int b = m >> 11;
                    const int t = m & 2047;
#pragma unroll
                    for (int in = 0; in < 2; in++) {
                        const int d = in * 16 + lr;
                        const float x1 = acc[im][in][r];
                        const float x2 = acc[im][in + 2][r];
                        const float c = cosb[t * 64 + d];
                        const float s = sinb[t * 64 + d];
                        float y1 = x1 * c - x2 * s;
                        float y2 = x2 * c + x1 * s;
                        if (isq) {
                            y1 *= qs; y2 *= qs;
                            const size_t base =
                                ((size_t)(b * 16 + j) * 2048 + t) * 64 + d;
                            q_ws[base] = (bf16_t)y1;
                            q_ws[base + 32] = (bf16_t)y2;
                        } else {
                            const int bh = b * 16 + (j - 16);
                            const size_t off =
                                ((size_t)(bh * 128 + (t >> 4)) * 2) * 512 +
                                ((t & 15) + (d >> 3) * 16) * 8 + (d & 7);
                            k_ws[off] = (bf16_t)y1;
                            k_ws[off + 512] = (bf16_t)y2;
                        }
                    }
                }
            }
        } else {
#pragma unroll
            for (int im = 0; im < IM; im++)
#pragma unroll
                for (int in = 0; in < 4; in++)
#pragma unroll
                    for (int r = 0; r < 4; r++) {
                        const int m = m0 + wm + im * 16 + quad * 4 + r;
                        const int b = m >> 11;
                        const int t = m & 2047;
                        const int d = in * 16 + lr;
                        const int bh = b * 16 + (j - 32);
                        const size_t off =
                            ((size_t)(bh * 64 + (t >> 5)) * 4 + (d >> 4)) * 512 +
                            ((d & 15) + ((t & 31) >> 3) * 16) * 8 + (t & 7);
                        v_ws[off] = (bf16_t)acc[im][in][r];
                    }
        }
    }
}

// ---------------------------------------------------------------------------
// Flash attention, 2 Q-fragments per wave (double arithmetic intensity):
// WG = 64 queries, 128 threads (2 waves x 32 queries). K/V loads shared by
// both fragments -> 2x MFMA per load byte; grid-wide iterations halved.
// Grid 1024 WGs (4 blocks/CU, 8 waves/CU), LPT. Transposed-score, max-free,
// LDS/barrier-free; only kb==qt intersects the causal diagonal (both frags).
// ---------------------------------------------------------------------------
__global__ __launch_bounds__(128) void attn_kernel(const bf16_t* __restrict__ q_ws,
                                                   const bf16_t* __restrict__ k_ws,
                                                   const bf16_t* __restrict__ v_ws,
                                                   bf16_t* __restrict__ ctx) {
    const int tid = threadIdx.x;
    const int w = tid >> 6;          // 0..1
    const int lane = tid & 63;
    const int lr = lane & 15;
    const int quad = lane >> 4;
    const int bh = blockIdx.x & 31;
    const int qt = 31 - (blockIdx.x >> 5);  // LPT: longest first
    const int b = bh >> 4;
    const int hd = bh & 15;
    const int trow0 = qt * 64 + w * 32;     // frag0 rows
    const int trow1 = trow0 + 16;           // frag1 rows
    const int query0 = trow0 + lr;
    const int query1 = trow1 + lr;

    const bf16_t* kbase = k_ws + (size_t)bh * 131072 + lane * 8;
    const bf16_t* vbase = v_ws + (size_t)bh * 131072 + lane * 8;

    const bf16_t* qb0 = q_ws + ((size_t)bh * 2048 + query0) * 64 + quad * 8;
    const bf16_t* qb1 = q_ws + ((size_t)bh * 2048 + query1) * 64 + quad * 8;
    const bf16x8 q0lo = *(const bf16x8*)qb0;
    const bf16x8 q0hi = *(const bf16x8*)(qb0 + 32);
    const bf16x8 q1lo = *(const bf16x8*)qb1;
    const bf16x8 q1hi = *(const bf16x8*)(qb1 + 32);

    f32x4 o0[4] = {}, o1[4] = {};
    float l0 = 0.0f, l1 = 0.0f;

    // K chunk address: ((kb*4+n)*2 + half)*512 ; V: ((kb*2+hh)*4 + n)*512
    bf16x8 kc[8];
#pragma unroll
    for (int n = 0; n < 4; n++) {
        kc[2 * n] = *(const bf16x8*)(kbase + (size_t)(n * 2) * 512);
        kc[2 * n + 1] = *(const bf16x8*)(kbase + (size_t)(n * 2 + 1) * 512);
    }

    for (int kb = 0; kb <= qt; kb++) {
        // V(kb): consumed at body end -> full-body latency cover
        bf16x8 vv[2][4];
#pragma unroll
        for (int hh = 0; hh < 2; hh++)
#pragma unroll
            for (int n = 0; n < 4; n++)
                vv[hh][n] = *(const bf16x8*)(vbase +
                    (size_t)((kb * 2 + hh) * 4 + n) * 512);

        // K(kb+1) prefetch
        const int kbn = (kb < qt) ? kb + 1 : kb;
        bf16x8 kn[8];
#pragma unroll
        for (int n = 0; n < 4; n++) {
            kn[2 * n] = *(const bf16x8*)(kbase + (size_t)((kbn * 4 + n) * 2) * 512);
            kn[2 * n + 1] = *(const bf16x8*)(kbase + (size_t)((kbn * 4 + n) * 2 + 1) * 512);
        }

        const int u0 = kb * 64;
        f32x4 s0[4], s1[4];
#pragma unroll
        for (int n = 0; n < 4; n++) {
            const f32x4 z = {};
            s0[n] = MFMA16(kc[2 * n], q0lo, z);
            s0[n] = MFMA16(kc[2 * n + 1], q0hi, s0[n]);
            s1[n] = MFMA16(kc[2 * n], q1lo, z);
            s1[n] = MFMA16(kc[2 * n + 1], q1hi, s1[n]);
        }

        if (kb == qt) {  // diagonal block: causal mask (key > query), both frags
#pragma unroll
            for (int n = 0; n < 4; n++)
#pragma unroll
                for (int r = 0; r < 4; r++) {
                    const int key = u0 + n * 16 + quad * 4 + r;
                    if (key > query0) s0[n][r] = -1e9f;
                    if (key > query1) s1[n][r] = -1e9f;
                }
        }

        bf16x4 pb0[4], pb1[4];
        float rs0 = 0.0f, rs1 = 0.0f;
#pragma unroll
        for (int n = 0; n < 4; n++) {
#pragma unroll
            for (int r = 0; r < 4; r++) {
                const float e0 = EXP2(s0[n][r]);
                const float e1 = EXP2(s1[n][r]);
                rs0 += e0; rs1 += e1;
                pb0[n][r] = (bf16_t)e0;
                pb1[n][r] = (bf16_t)e1;
            }
        }
        l0 += rs0;
        l1 += rs1;

#pragma unroll
        for (int hh = 0; hh < 2; hh++) {  // 32-key halves
            const bf16x8 pf0 = ptrans(pb0[2 * hh], pb0[2 * hh + 1], quad, lr);
            const bf16x8 pf1 = ptrans(pb1[2 * hh], pb1[2 * hh + 1], quad, lr);
#pragma unroll
            for (int n = 0; n < 4; n++) {
                o0[n] = MFMA16(vv[hh][n], pf0, o0[n]);
                o1[n] = MFMA16(vv[hh][n], pf1, o1[n]);
            }
        }

#pragma unroll
        for (int i = 0; i < 8; i++) kc[i] = kn[i];
    }

    // final l reductions across the 4 quads holding each query's keys
    l0 += __shfl_xor(l0, 16);
    l0 += __shfl_xor(l0, 32);
    l1 += __shfl_xor(l1, 16);
    l1 += __shfl_xor(l1, 32);

    const float inv0 = 1.0f / fmaxf(l0, 1e-30f);
    const float inv1 = 1.0f / fmaxf(l1, 1e-30f);
    const size_t base0 = ((size_t)b * 2048 + query0) * 1024 + hd * 64 + quad * 4;
    const size_t base1 = ((size_t)b * 2048 + query1) * 1024 + hd * 64 + quad * 4;
#pragma unroll
    for (int n = 0; n < 4; n++) {
        bf16x4 ob0, ob1;
#pragma unroll
        for (int r = 0; r < 4; r++) {
            ob0[r] = (bf16_t)(o0[n][r] * inv0);
            ob1[r] = (bf16_t)(o1[n][r] * inv1);
        }
        *(bf16x4*)&ctx[base0 + n * 16] = ob0;
        *(bf16x4*)&ctx[base1 + n * 16] = ob1;
    }
}

// ---------------------------------------------------------------------------
// Launcher. Inputs fp32, output fp32.
// ws bytes: [0,8M) hs_b -> (after gemm1) ctx overlay | [8M,14M) wqkv_b |
//           [14M,16M) wo_b | [16M,24M) q | [24M,32M) k | [32M,40M) v.
// ---------------------------------------------------------------------------
extern "C" void kernel_launch(void* const* d_in, const int* in_sizes, int n_in,
                              void* d_out, int out_size, void* d_ws, size_t ws_size,
                              hipStream_t stream) {
    const float* hs = (const float*)d_in[0];
    const float* cosb = (const float*)d_in[1];
    const float* sinb = (const float*)d_in[2];
    const float* wqkv = (const float*)d_in[3];
    const float* wo = (const float*)d_in[4];
    float* out = (float*)d_out;

    char* ws = (char*)d_ws;
    bf16_t* hs_b = (bf16_t*)(ws);
    bf16_t* wqkv_b = hs_b + 4194304;
    bf16_t* wo_b = hs_b + 7340032;
    bf16_t* q_ws = (bf16_t*)(ws + (size_t)(16u << 20));
    bf16_t* k_ws = (bf16_t*)(ws + (size_t)(24u << 20));
    bf16_t* v_ws = (bf16_t*)(ws + (size_t)(32u << 20));
    bf16_t* ctx = (bf16_t*)(ws);  // overlays hs_b (dead after gemm1)

    // 0) fp32 -> bf16 convert (hs | wqkv | wo packed)
    convert_kernel<<<dim3(4096), dim3(256), 0, stream>>>(hs, wqkv, wo, hs_b);

    // 1) QKV projection + fused RoPE + scatter: M=4096, N=3072, K=1024
    gemm_bt<1, 3072, 128><<<dim3(24, 32), dim3(256), 0, stream>>>(
        hs_b, wqkv_b, nullptr, q_ws, k_ws, v_ws, cosb, sinb);

    // 2) Flash attention (2 Q-frags/wave, 128-thread WGs) -> ctx (bf16)
    attn_kernel<<<dim3(1024), dim3(128), 0, stream>>>(q_ws, k_ws, v_ws, ctx);

    // 3) Output projection: M=4096, N=1024, K=1024 (BM=64 -> 512 blocks)
    gemm_bt<0, 1024, 64><<<dim3(8, 64), dim3(256), 0, stream>>>(
        ctx, wo_b, out, nullptr, nullptr, nullptr, nullptr, nullptr);
}

// Round 17
// 178.144 us; speedup vs baseline: 1.1424x; 1.0238x over previous
//
#include <hip/hip_runtime.h>

typedef __bf16 bf16_t;
typedef __bf16 bf16x4 __attribute__((ext_vector_type(4)));
typedef __bf16 bf16x8 __attribute__((ext_vector_type(8)));
typedef float f32x4 __attribute__((ext_vector_type(4)));
typedef unsigned int u32x2 __attribute__((ext_vector_type(2)));
typedef unsigned long long u64;

#define MFMA16(a, b, c) __builtin_amdgcn_mfma_f32_16x16x32_bf16((a), (b), (c), 0, 0, 0)

#define LDG2LDS16(g, l)                                                        \
    __builtin_amdgcn_global_load_lds(                                          \
        (const __attribute__((address_space(1))) void*)(g),                    \
        (__attribute__((address_space(3))) void*)(l), 16, 0, 0)

#if __has_builtin(__builtin_amdgcn_exp2f)
#define EXP2(x) __builtin_amdgcn_exp2f(x)
#else
#define EXP2(x) exp2f(x)
#endif

// load 8 consecutive fp32 as bf16x8
__device__ inline bf16x8 load8(const float* p) {
    const f32x4 a = *(const f32x4*)p;
    const f32x4 b = *(const f32x4*)(p + 4);
    bf16x8 r;
#pragma unroll
    for (int i = 0; i < 4; i++) { r[i] = (bf16_t)a[i]; r[4 + i] = (bf16_t)b[i]; }
    return r;
}

__device__ inline u32x2 as2(bf16x4 v) {
    u32x2 r;
    __builtin_memcpy(&r, &v, 8);
    return r;
}

// 8-byte cross-lane shuffle of a packed bf16x4 (fallback path)
__device__ inline bf16x4 shfl4(bf16x4 v, int src) {
    u64 x;
    __builtin_memcpy(&x, &v, 8);
    x = __shfl(x, src, 64);
    bf16x4 r;
    __builtin_memcpy(&r, &x, 8);
    return r;
}

// P C-layout (2 packed bf16x4 regs = 32 keys x this query) -> PV B-fragment,
// via 6 permlane-swaps (HW-verified r13); ds_bpermute fallback.
__device__ inline bf16x8 ptrans(bf16x4 pA, bf16x4 pB, int quad, int lr) {
    bf16x8 pf;
#if __has_builtin(__builtin_amdgcn_permlane16_swap) && \
    __has_builtin(__builtin_amdgcn_permlane32_swap)
    const u32x2 P0 = as2(pA);
    const u32x2 P1 = as2(pB);
    const u32x2 s1a = __builtin_amdgcn_permlane16_swap(P0[0], P0[1], false, false);
    const u32x2 s1b = __builtin_amdgcn_permlane16_swap(P1[0], P1[1], false, false);
    const u32x2 s2a = __builtin_amdgcn_permlane32_swap(s1a[0], s1b[0], false, false);
    const u32x2 s2b = __builtin_amdgcn_permlane32_swap(s1a[1], s1b[1], false, false);
    const u32x2 s3a = __builtin_amdgcn_permlane16_swap(s2a[0], s2a[1], false, false);
    const u32x2 s3b = __builtin_amdgcn_permlane16_swap(s2b[0], s2b[1], false, false);
    const unsigned pfd[4] = {s3a[0], s3a[1], s3b[0], s3b[1]};
    __builtin_memcpy(&pf, pfd, 16);
#else
    const int srcLow = ((quad & 1) << 5) + lr;
    const int srcHigh = srcLow + 16;
    const bool loSel = (quad < 2);
    const bf16x4 a0 = shfl4(pA, srcLow);
    const bf16x4 a1 = shfl4(pB, srcLow);
    const bf16x4 b0 = shfl4(pA, srcHigh);
    const bf16x4 b1 = shfl4(pB, srcHigh);
    const bf16x4 lo = loSel ? a0 : a1;
    const bf16x4 hi = loSel ? b0 : b1;
#pragma unroll
    for (int r = 0; r < 4; r++) { pf[r] = lo[r]; pf[4 + r] = hi[r]; }
#endif
    return pf;
}

// ---------------------------------------------------------------------------
// fp32 -> bf16 convert: hs (4194304 el) | wqkv (3145728 el) | wo (1048576 el)
// ---------------------------------------------------------------------------
__global__ __launch_bounds__(256) void convert_kernel(const float* __restrict__ hs,
                                                      const float* __restrict__ wqkv,
                                                      const float* __restrict__ wo,
                                                      bf16_t* __restrict__ outb) {
    const size_t c = ((size_t)blockIdx.x * 256 + threadIdx.x) * 8;
    const float* src;
    size_t off;
    if (c < 4194304) { src = hs; off = c; }
    else if (c < 7340032) { src = wqkv; off = c - 4194304; }
    else { src = wo; off = c - 7340032; }
    *(bf16x8*)(outb + c) = load8(src + off);
}

// ---------------------------------------------------------------------------
// K/V swizzled layouts (MFMA-fragment order -> attn loads are base+lane*16):
//   k_sw: ((bh*128 + t>>4)*2 + (d>>5))*512 + ((t&15)+16*((d&31)>>3))*8 + (d&7)
//   v_sw: ((bh*64 + t>>5)*4 + (d>>4))*512 + ((d&15)+16*((t&31)>>3))*8 + (t&7)
// ---------------------------------------------------------------------------

// GEMM (r13-proven): m97 DMA staging, row-major LDS stride 32, BK=32.
// MODE 0: store C row-major fp32 to outp (N = NDIM)
// MODE 1: qkv scatter epilogue with fused RoPE (wave-uniform head slot j)
template <int MODE, int NDIM, int BM>
__global__ __launch_bounds__(256) void gemm_bt(const bf16_t* __restrict__ A,
                                               const bf16_t* __restrict__ B,
                                               float* __restrict__ outp,
                                               bf16_t* __restrict__ q_ws,
                                               bf16_t* __restrict__ k_ws,
                                               bf16_t* __restrict__ v_ws,
                                               const float* __restrict__ cosb,
                                               const float* __restrict__ sinb) {
    constexpr int K = 1024;
    constexpr int IM = BM / 32;
    __shared__ __align__(16) bf16_t As[BM * 32];
    __shared__ __align__(16) bf16_t Bs[128 * 32];

    const int tid = threadIdx.x;
    const int w = tid >> 6;
    const int lane = tid & 63;
    const int lr = lane & 15;
    const int quad = lane >> 4;
    const int m0 = blockIdx.y * BM;
    const int n0 = blockIdx.x * 128;
    const int wm = (w & 1) * (BM / 2);
    const int wn = (w >> 1) * 64;

    const int srow = tid >> 2;
    const int skk = (tid & 3) * 8;
    const bf16_t* gA0 = A + (size_t)(m0 + srow) * K + skk;
    const bf16_t* gA1 = gA0 + (size_t)64 * K;  // only when BM==128
    const bf16_t* gB0 = B + (size_t)(n0 + srow) * K + skk;
    const bf16_t* gB1 = gB0 + (size_t)64 * K;
    bf16_t* lA0 = As + w * 512;
    bf16_t* lA1 = As + 2048 + w * 512;
    bf16_t* lB0 = Bs + w * 512;
    bf16_t* lB1 = Bs + 2048 + w * 512;

    f32x4 acc[IM][4] = {};

    for (int k0 = 0; k0 < K; k0 += 32) {
        LDG2LDS16(gA0 + k0, lA0);
        if constexpr (BM == 128) LDG2LDS16(gA1 + k0, lA1);
        LDG2LDS16(gB0 + k0, lB0);
        LDG2LDS16(gB1 + k0, lB1);
        __syncthreads();

        bf16x8 af[IM], bfm[4];
#pragma unroll
        for (int im = 0; im < IM; im++)
            af[im] = *(const bf16x8*)&As[(wm + im * 16 + lr) * 32 + quad * 8];
#pragma unroll
        for (int in = 0; in < 4; in++)
            bfm[in] = *(const bf16x8*)&Bs[(wn + in * 16 + lr) * 32 + quad * 8];
#pragma unroll
        for (int im = 0; im < IM; im++)
#pragma unroll
            for (int in = 0; in < 4; in++)
                acc[im][in] = MFMA16(af[im], bfm[in], acc[im][in]);
        __syncthreads();
    }

    if constexpr (MODE == 0) {
#pragma unroll
        for (int im = 0; im < IM; im++)
#pragma unroll
            for (int in = 0; in < 4; in++)
#pragma unroll
                for (int r = 0; r < 4; r++) {
                    const int m = m0 + wm + im * 16 + quad * 4 + r;
                    const int n = n0 + wn + in * 16 + lr;
                    outp[(size_t)m * NDIM + n] = acc[im][in][r];
                }
    } else {
        const int j = (n0 + wn) >> 6;
        if (j < 32) {
            const bool isq = (j < 16);
            const float qs = 0.125f * 1.44269504089f;
#pragma unroll
            for (int im = 0; im < IM; im++) {
#pragma unroll
                for (int r = 0; r < 4; r++) {
                    const int m = m0 + wm + im * 16 + quad * 4 + r;
                    const int b = m >> 11;
                    const int t = m & 2047;
#pragma unroll
                    for (int in = 0; in < 2; in++) {
                        const int d = in * 16 + lr;
                        const float x1 = acc[im][in][r];
                        const float x2 = acc[im][in + 2][r];
                        const float c = cosb[t * 64 + d];
                        const float s = sinb[t * 64 + d];
                        float y1 = x1 * c - x2 * s;
                        float y2 = x2 * c + x1 * s;
                        if (isq) {
                            y1 *= qs; y2 *= qs;
                            const size_t base =
                                ((size_t)(b * 16 + j) * 2048 + t) * 64 + d;
                            q_ws[base] = (bf16_t)y1;
                            q_ws[base + 32] = (bf16_t)y2;
                        } else {
                            const int bh = b * 16 + (j - 16);
                            const size_t off =
                                ((size_t)(bh * 128 + (t >> 4)) * 2) * 512 +
                                ((t & 15) + (d >> 3) * 16) * 8 + (d & 7);
                            k_ws[off] = (bf16_t)y1;
                            k_ws[off + 512] = (bf16_t)y2;
                        }
                    }
                }
            }
        } else {
#pragma unroll
            for (int im = 0; im < IM; im++)
#pragma unroll
                for (int in = 0; in < 4; in++)
#pragma unroll
                    for (int r = 0; r < 4; r++) {
                        const int m = m0 + wm + im * 16 + quad * 4 + r;
                        const int b = m >> 11;
                        const int t = m & 2047;
                        const int d = in * 16 + lr;
                        const int bh = b * 16 + (j - 32);
                        const size_t off =
                            ((size_t)(bh * 64 + (t >> 5)) * 4 + (d >> 4)) * 512 +
                            ((d & 15) + ((t & 31) >> 3) * 16) * 8 + (t & 7);
                        v_ws[off] = (bf16_t)acc[im][in][r];
                    }
        }
    }
}

// ---------------------------------------------------------------------------
// Flash attention, 2 Q-fragments per wave (r16) WITHOUT the K register
// double-buffer: K loaded at body top (before V, so the QK waitcnt drains
// only K while V stays in flight across softmax). Saves ~32 VGPRs + 32
// v_mov/iter; cross-wave interleave (2 waves/SIMD) covers K L2 latency.
// WG = 64 queries, 128 threads (2 waves x 32 queries); grid 1024 WGs, LPT.
// Transposed-score, max-free, LDS/barrier-free.
// ---------------------------------------------------------------------------
__global__ __launch_bounds__(128) void attn_kernel(const bf16_t* __restrict__ q_ws,
                                                   const bf16_t* __restrict__ k_ws,
                                                   const bf16_t* __restrict__ v_ws,
                                                   bf16_t* __restrict__ ctx) {
    const int tid = threadIdx.x;
    const int w = tid >> 6;          // 0..1
    const int lane = tid & 63;
    const int lr = lane & 15;
    const int quad = lane >> 4;
    const int bh = blockIdx.x & 31;
    const int qt = 31 - (blockIdx.x >> 5);  // LPT: longest first
    const int b = bh >> 4;
    const int hd = bh & 15;
    const int trow0 = qt * 64 + w * 32;     // frag0 rows
    const int trow1 = trow0 + 16;           // frag1 rows
    const int query0 = trow0 + lr;
    const int query1 = trow1 + lr;

    const bf16_t* kbase = k_ws + (size_t)bh * 131072 + lane * 8;
    const bf16_t* vbase = v_ws + (size_t)bh * 131072 + lane * 8;

    const bf16_t* qb0 = q_ws + ((size_t)bh * 2048 + query0) * 64 + quad * 8;
    const bf16_t* qb1 = q_ws + ((size_t)bh * 2048 + query1) * 64 + quad * 8;
    const bf16x8 q0lo = *(const bf16x8*)qb0;
    const bf16x8 q0hi = *(const bf16x8*)(qb0 + 32);
    const bf16x8 q1lo = *(const bf16x8*)qb1;
    const bf16x8 q1hi = *(const bf16x8*)(qb1 + 32);

    f32x4 o0[4] = {}, o1[4] = {};
    float l0 = 0.0f, l1 = 0.0f;

    for (int kb = 0; kb <= qt; kb++) {
        // K(kb) first (drained by QK waitcnt), then V(kb) (stays in flight
        // until the PV MFMAs -> covered by QK + softmax)
        bf16x8 kc[8];
#pragma unroll
        for (int n = 0; n < 4; n++) {
            kc[2 * n] = *(const bf16x8*)(kbase + (size_t)((kb * 4 + n) * 2) * 512);
            kc[2 * n + 1] = *(const bf16x8*)(kbase + (size_t)((kb * 4 + n) * 2 + 1) * 512);
        }
        bf16x8 vv[2][4];
#pragma unroll
        for (int hh = 0; hh < 2; hh++)
#pragma unroll
            for (int n = 0; n < 4; n++)
                vv[hh][n] = *(const bf16x8*)(vbase +
                    (size_t)((kb * 2 + hh) * 4 + n) * 512);

        const int u0 = kb * 64;
        f32x4 s0[4], s1[4];
#pragma unroll
        for (int n = 0; n < 4; n++) {
            const f32x4 z = {};
            s0[n] = MFMA16(kc[2 * n], q0lo, z);
            s0[n] = MFMA16(kc[2 * n + 1], q0hi, s0[n]);
            s1[n] = MFMA16(kc[2 * n], q1lo, z);
            s1[n] = MFMA16(kc[2 * n + 1], q1hi, s1[n]);
        }

        if (kb == qt) {  // diagonal block: causal mask (key > query), both frags
#pragma unroll
            for (int n = 0; n < 4; n++)
#pragma unroll
                for (int r = 0; r < 4; r++) {
                    const int key = u0 + n * 16 + quad * 4 + r;
                    if (key > query0) s0[n][r] = -1e9f;
                    if (key > query1) s1[n][r] = -1e9f;
                }
        }

        bf16x4 pb0[4], pb1[4];
        float rs0 = 0.0f, rs1 = 0.0f;
#pragma unroll
        for (int n = 0; n < 4; n++) {
#pragma unroll
            for (int r = 0; r < 4; r++) {
                const float e0 = EXP2(s0[n][r]);
                const float e1 = EXP2(s1[n][r]);
                rs0 += e0; rs1 += e1;
                pb0[n][r] = (bf16_t)e0;
                pb1[n][r] = (bf16_t)e1;
            }
        }
        l0 += rs0;
        l1 += rs1;

#pragma unroll
        for (int hh = 0; hh < 2; hh++) {  // 32-key halves
            const bf16x8 pf0 = ptrans(pb0[2 * hh], pb0[2 * hh + 1], quad, lr);
            const bf16x8 pf1 = ptrans(pb1[2 * hh], pb1[2 * hh + 1], quad, lr);
#pragma unroll
            for (int n = 0; n < 4; n++) {
                o0[n] = MFMA16(vv[hh][n], pf0, o0[n]);
                o1[n] = MFMA16(vv[hh][n], pf1, o1[n]);
            }
        }
    }

    // final l reductions across the 4 quads holding each query's keys
    l0 += __shfl_xor(l0, 16);
    l0 += __shfl_xor(l0, 32);
    l1 += __shfl_xor(l1, 16);
    l1 += __shfl_xor(l1, 32);

    const float inv0 = 1.0f / fmaxf(l0, 1e-30f);
    const float inv1 = 1.0f / fmaxf(l1, 1e-30f);
    const size_t base0 = ((size_t)b * 2048 + query0) * 1024 + hd * 64 + quad * 4;
    const size_t base1 = ((size_t)b * 2048 + query1) * 1024 + hd * 64 + quad * 4;
#pragma unroll
    for (int n = 0; n < 4; n++) {
        bf16x4 ob0, ob1;
#pragma unroll
        for (int r = 0; r < 4; r++) {
            ob0[r] = (bf16_t)(o0[n][r] * inv0);
            ob1[r] = (bf16_t)(o1[n][r] * inv1);
        }
        *(bf16x4*)&ctx[base0 + n * 16] = ob0;
        *(bf16x4*)&ctx[base1 + n * 16] = ob1;
    }
}

// ---------------------------------------------------------------------------
// Launcher. Inputs fp32, output fp32.
// ws bytes: [0,8M) hs_b -> (after gemm1) ctx overlay | [8M,14M) wqkv_b |
//           [14M,16M) wo_b | [16M,24M) q | [24M,32M) k | [32M,40M) v.
// ---------------------------------------------------------------------------
extern "C" void kernel_launch(void* const* d_in, const int* in_sizes, int n_in,
                              void* d_out, int out_size, void* d_ws, size_t ws_size,
                              hipStream_t stream) {
    const float* hs = (const float*)d_in[0];
    const float* cosb = (const float*)d_in[1];
    const float* sinb = (const float*)d_in[2];
    const float* wqkv = (const float*)d_in[3];
    const float* wo = (const float*)d_in[4];
    float* out = (float*)d_out;

    char* ws = (char*)d_ws;
    bf16_t* hs_b = (bf16_t*)(ws);
    bf16_t* wqkv_b = hs_b + 4194304;
    bf16_t* wo_b = hs_b + 7340032;
    bf16_t* q_ws = (bf16_t*)(ws + (size_t)(16u << 20));
    bf16_t* k_ws = (bf16_t*)(ws + (size_t)(24u << 20));
    bf16_t* v_ws = (bf16_t*)(ws + (size_t)(32u << 20));
    bf16_t* ctx = (bf16_t*)(ws);  // overlays hs_b (dead after gemm1)

    // 0) fp32 -> bf16 convert (hs | wqkv | wo packed)
    convert_kernel<<<dim3(4096), dim3(256), 0, stream>>>(hs, wqkv, wo, hs_b);

    // 1) QKV projection + fused RoPE + scatter: M=4096, N=3072, K=1024
    gemm_bt<1, 3072, 128><<<dim3(24, 32), dim3(256), 0, stream>>>(
        hs_b, wqkv_b, nullptr, q_ws, k_ws, v_ws, cosb, sinb);

    // 2) Flash attention (2 Q-frags/wave, 128-thread WGs) -> ctx (bf16)
    attn_kernel<<<dim3(1024), dim3(128), 0, stream>>>(q_ws, k_ws, v_ws, ctx);

    // 3) Output projection: M=4096, N=1024, K=1024 (BM=64 -> 512 blocks)
    gemm_bt<0, 1024, 64><<<dim3(8, 64), dim3(256), 0, stream>>>(
        ctx, wo_b, out, nullptr, nullptr, nullptr, nullptr, nullptr);
}